// Round 11
// baseline (145.385 us; speedup 1.0000x reference)
//
#include <hip/hip_runtime.h>

// LSA: x(8,1024,512) -> qkv -> 8-head attention (N=1024, D=64, diag masked,
// learnable temperature) -> out proj. I/O fp32; bf16 MFMA, fp32 accum.
// B=8, N=1024, DIM=512, H=8, Dh=64, INNER=512.

typedef __attribute__((ext_vector_type(8)))  short    short8;
typedef __attribute__((ext_vector_type(8)))  __bf16   bf16x8;
typedef __attribute__((ext_vector_type(4)))  float    floatx4;
typedef __attribute__((ext_vector_type(16))) float    floatx16;
typedef __attribute__((ext_vector_type(4)))  unsigned uint4v;
typedef __attribute__((ext_vector_type(2)))  unsigned uint2v;

#define DEV static __device__ __forceinline__
#define AS1 __attribute__((address_space(1)))
#define AS3 __attribute__((address_space(3)))

DEV unsigned fbits(float f) { union { float f; unsigned u; } v; v.f = f; return v.u; }
DEV short f2bf_r(float f) {            // round-half-up f32->bf16: 2 ops
    return (short)((fbits(f) + 0x8000u) >> 16);
}
DEV unsigned pack2r(float a, float b) {  // [b|a] bf16 pair: add,add,v_perm = 3 ops
    return __builtin_amdgcn_perm(fbits(b) + 0x8000u, fbits(a) + 0x8000u, 0x07060302u);
}
DEV floatx4 mfma16(short8 a, short8 b, floatx4 c) {
    return __builtin_amdgcn_mfma_f32_16x16x32_bf16(
        __builtin_bit_cast(bf16x8, a), __builtin_bit_cast(bf16x8, b), c, 0, 0, 0);
}
DEV floatx16 mfma32(short8 a, short8 b, floatx16 c) {
    return __builtin_amdgcn_mfma_f32_32x32x16_bf16(
        __builtin_bit_cast(bf16x8, a), __builtin_bit_cast(bf16x8, b), c, 0, 0, 0);
}
// async global->LDS, 16B per lane. l must be the wave-uniform base (lane 0 slot).
DEV void async16(const void* g, void* l) {
    __builtin_amdgcn_global_load_lds((AS1 void*)(unsigned long long)g,
                                     (AS3 void*)l, 16, 0, 0);
}

// ------------- prep: x fp32->bf16 ; LDS-tiled transpose+convert of weights --------
__global__ void prep(const float* __restrict__ x, const float* __restrict__ wqkv,
                     const float* __restrict__ wout, short* __restrict__ Xb,
                     short* __restrict__ wt1, short* __restrict__ wt2) {
    const int bid = blockIdx.x, tid = threadIdx.x;
    if (bid < 2048) {                       // x: 4,194,304 elems, 8/thread
        int base = bid * 2048 + tid * 8;
        float4 f0 = *(const float4*)&x[base];
        float4 f1 = *(const float4*)&x[base + 4];
        uint4v s = { pack2r(f0.x, f0.y), pack2r(f0.z, f0.w),
                     pack2r(f1.x, f1.y), pack2r(f1.z, f1.w) };
        *(uint4v*)&Xb[base] = s;
        return;
    }
    // transpose 64x64 tiles: wqkv [512k][1536n] -> wt1 [1536][512];
    //                        wout [512k][512n]  -> wt2 [512][512]
    __shared__ short Ts[64][65];
    int t = bid - 2048;
    const float* src; short* dst; int srcld, n0, k0;
    if (t < 192) { int tn = t % 24, tk = t / 24; n0 = tn * 64; k0 = tk * 64;
                   src = wqkv; srcld = 1536; dst = wt1; }
    else { t -= 192; int tn = t & 7, tk = t >> 3; n0 = tn * 64; k0 = tk * 64;
           src = wout; srcld = 512; dst = wt2; }
#pragma unroll
    for (int it = 0; it < 16; it++) {       // coalesced read (consecutive n)
        int idx = it * 256 + tid, rk = idx >> 6, cn = idx & 63;
        Ts[cn][rk] = f2bf_r(src[(k0 + rk) * srcld + n0 + cn]);
    }
    __syncthreads();
#pragma unroll
    for (int it = 0; it < 16; it++) {       // coalesced write (consecutive k)
        int idx = it * 256 + tid, rn = idx >> 6, ck = idx & 63;
        dst[(n0 + rn) * 512 + k0 + ck] = Ts[rn][ck];
    }
}

// ------------- GEMM: C(8192 x N) = A(8192x512) * Bt(Nx512)^T ----------------------
// m97 pattern: unpadded LDS, global_load_lds width-16, XOR-chunk swizzle for
// conflict-free ds_read_b128. MODE 0: N=1536, LDS-routed epilogue -> Q,K,Vt (bf16,
// all 16B coalesced stores). MODE 1: N=512, fp32 bias + fp32 store.
// bounds(256,3): cap VGPR ~170 so all 768 gemm1 blocks are co-resident (3/CU).
template<int MODE>
__global__ __launch_bounds__(256, 3)
void gemm128(const short* __restrict__ A, const short* __restrict__ Bt,
             const float* __restrict__ temp,
             short* __restrict__ Qb, short* __restrict__ Kb, short* __restrict__ Vtb,
             float* __restrict__ Op, const float* __restrict__ bias) {
    union SMem {
        struct { short As[128 * 64]; short Bs[128 * 64]; } t;
        short Ts[128 * 130];                // epilogue re-layout scratch (+2 pad)
    };
    __shared__ __align__(16) SMem sm;

    const int tid  = threadIdx.x;
    const int lane = tid & 63, w = tid >> 6;
    const int wr = (w >> 1) * 64, wc = (w & 1) * 64;
    const int l15 = lane & 15, quad = lane >> 4;
    const int m0 = blockIdx.x * 128, n0 = blockIdx.y * 128;

    floatx4 acc[4][4];
#pragma unroll
    for (int i = 0; i < 4; i++)
#pragma unroll
        for (int j = 0; j < 4; j++) acc[i][j] = (floatx4)0.f;

    // staging: slot s holds row r=s>>3, chunk cc=s&7; LDS chunk cc = global chunk cc^(r&7)
    const int sr = (tid >> 3), scc = tid & 7;
    for (int kt = 0; kt < 512; kt += 64) {
#pragma unroll
        for (int it = 0; it < 4; it++) {
            int r = it * 32 + sr;                       // slot = it*256 + tid
            int gcol = kt + ((scc ^ (r & 7)) * 8);
            async16(&A[(m0 + r) * 512 + gcol], sm.t.As + (it * 256 + w * 64) * 8);
            async16(&Bt[(n0 + r) * 512 + gcol], sm.t.Bs + (it * 256 + w * 64) * 8);
        }
        __syncthreads();
#pragma unroll
        for (int k2 = 0; k2 < 2; k2++) {
            const int cS = ((k2 * 4 + quad) ^ (l15 & 7)) * 8;
            short8 af[4], bf[4];
#pragma unroll
            for (int i = 0; i < 4; i++) {
                af[i] = *(const short8*)&sm.t.As[(wr + i * 16 + l15) * 64 + cS];
                bf[i] = *(const short8*)&sm.t.Bs[(wc + i * 16 + l15) * 64 + cS];
            }
#pragma unroll
            for (int i = 0; i < 4; i++)
#pragma unroll
                for (int j = 0; j < 4; j++)
                    acc[i][j] = mfma16(af[i], bf[j], acc[i][j]);
        }
        __syncthreads();
    }

    // C/D layout: col = lane&15, row = quad*4 + reg
    if (MODE == 1) {
#pragma unroll
        for (int i = 0; i < 4; i++) {
            int mrow = m0 + wr + i * 16 + quad * 4;
#pragma unroll
            for (int j = 0; j < 4; j++) {
                int col = n0 + wc + j * 16 + l15;
                float b = bias[col];
#pragma unroll
                for (int r = 0; r < 4; r++)
                    Op[(mrow + r) * 512 + col] = acc[i][j][r] + b;
            }
        }
        return;
    }

    // MODE 0: route through LDS so every global store is a coalesced short8.
    const int which = n0 >> 9;                 // 0=Q 1=K 2=V
    const float qs = (which == 0) ? __expf(temp[0]) * 1.44269504089f : 1.f;
    const bool isV = (which == 2);
#pragma unroll
    for (int i = 0; i < 4; i++)
#pragma unroll
        for (int j = 0; j < 4; j++) {
            int c  = wc + j * 16 + l15;
            int tt = wr + i * 16 + quad * 4;
#pragma unroll
            for (int r = 0; r < 4; r++) {
                short v = f2bf_r(acc[i][j][r] * qs);
                if (isV) sm.Ts[c * 130 + tt + r] = v;        // [col][token]
                else     sm.Ts[(tt + r) * 130 + c] = v;      // [token][col]
            }
        }
    __syncthreads();
    const int bb = m0 >> 10, tloc = m0 & 1023;
#pragma unroll
    for (int it = 0; it < 8; it++) {
        int s = it * 256 + tid;                // 2048 strips of 8 shorts
        int a = s >> 4, b8 = s & 15;
        short8 v = *(const short8*)&sm.Ts[a * 130 + b8 * 8];
        if (isV) {                             // a = col (vcol), b8*8 = token offset
            int vcol = n0 - 1024 + a;
            int bh = bb * 8 + (vcol >> 6), d = vcol & 63;
            *(short8*)&Vtb[(bh * 64 + d) * 1024 + tloc + b8 * 8] = v;
        } else {                               // a = token row, b8*8 = col offset
            int col = n0 + b8 * 8;
            int bh = bb * 8 + ((col >> 6) & 7), d0 = col & 63;
            short* dst = (which == 0) ? Qb : Kb;
            *(short8*)&dst[(bh * 1024 + tloc + a) * 64 + d0] = v;
        }
    }
}

// ------------- flash attention v9: 512 thr, 2 q-tiles/block, dbuf ------------------
// grid 256 = bh(64) x qpair(4); bh = blk & 63 (stride-64 = same XCD). 8 waves,
// wave w owns q rows qt*256 + w*32 .. +32. Halves per-CU staging count, global
// fetch, and barrier executions vs the 2-block/CU r10 version; MFMA/VALU per CU
// unchanged. LDS 67.6 KB dbuf -> 1 block/CU. (512,2): VGPR cap 256, no squeeze.
__global__ __launch_bounds__(512, 2)
void attn_kernel(const short* __restrict__ Q, const short* __restrict__ Kb,
                 const short* __restrict__ Vt, short* __restrict__ O) {
    __shared__ __align__(16) short Ks[2][16 * 528];   // K tiles [kv128][d64]  2x16.9 KB
    __shared__ __align__(16) short Vs[2][16 * 528];   // Vt tiles [d64][kv128] 2x16.9 KB

    const int tid  = threadIdx.x;
    const int lane = tid & 63, w = tid >> 6;       // 8 waves
    const int l31 = lane & 31, h = lane >> 5;
    const int bh = blockIdx.x & 63, qt = blockIdx.x >> 6;   // qt 0..3
    const int qrow = qt * 256 + w * 32 + l31;      // this lane's q row

    // staging lane constants (16 K-groups + 16 V-groups, 2 of each per wave)
    const int krow_off = lane >> 3, kchunk = ((lane & 7) ^ (lane >> 3)) * 8;
    const int vrow_off = lane >> 4, vcs = lane & 15;
    const short* Kbase = Kb + bh * 65536;
    const short* Vbase = Vt + bh * 65536;

    // prefetch tile 0 into buffer 0
#pragma unroll
    for (int it = 0; it < 2; it++) {
        int g = it * 8 + w;
        async16(&Kbase[(g * 8 + krow_off) * 64 + kchunk], Ks[0] + g * 528);
        int vr = g * 4 + vrow_off;
        async16(&Vbase[vr * 1024 + ((vcs ^ (vr & 15)) * 8)], Vs[0] + g * 528);
    }

    // Q B-frag (pre-scaled by exp(T)*log2e): B[n=q=lane&31][k=ks*16+h*8+j]
    const short* Qp = Q + (bh * 1024 + qrow) * 64;
    short8 qf[4];
#pragma unroll
    for (int ks = 0; ks < 4; ks++)
        qf[ks] = *(const short8*)&Qp[ks * 16 + h * 8];

    floatx16 accO[2];                              // O^T: d=dt*32+(reg&3)+8(reg>>2)+4h
    accO[0] = (floatx16)0.f; accO[1] = (floatx16)0.f;
    float ls0 = 0.f, ls1 = 0.f;                    // split row-sum chains (ILP)

    // diagonal: this wave's masked kv-tile and 32-kv subtile
    const int dtile = qt * 2 + (w >> 2), dsub = w & 3;
    const unsigned lanemask =
        (h == ((l31 >> 2) & 1)) ? (1u << ((l31 & 3) | (((l31 >> 3) & 3) << 2))) : 0u;

    for (int j = 0; j < 8; j++) {
        const int buf = j & 1;
        __syncthreads();                           // tile j landed; all past tile j-1

        if (j < 7) {                               // prefetch tile j+1 into other buf
            const int kv1 = (j + 1) * 128;
#pragma unroll
            for (int it = 0; it < 2; it++) {
                int g = it * 8 + w;
                async16(&Kbase[(kv1 + g * 8 + krow_off) * 64 + kchunk],
                        Ks[buf ^ 1] + g * 528);
                int vr = g * 4 + vrow_off;
                async16(&Vbase[vr * 1024 + kv1 + ((vcs ^ (vr & 15)) * 8)],
                        Vs[buf ^ 1] + g * 528);
            }
        }

        // S^T per 32-kv subtile; exp2 + pack immediately (keeps regs low)
        unsigned u[32];                            // P pairs: u[sub*8 + r2]
#pragma unroll
        for (int sub = 0; sub < 4; sub++) {
            floatx16 sacc = (floatx16)0.f;
#pragma unroll
            for (int ks = 0; ks < 4; ks++) {       // A(K)[m=kv][k]: row sub*32+l31
                const int grp = sub * 4 + (l31 >> 3);
                const int ck = ((2 * ks + h) ^ (l31 & 7)) * 8;
                short8 kf = *(const short8*)&Ks[buf][grp * 528 + (l31 & 7) * 64 + ck];
                sacc = mfma32(kf, qf[ks], sacc);
            }
            if (j == dtile && sub == dsub) {       // diagonal mask
#pragma unroll
                for (int r = 0; r < 16; r++)
                    if ((lanemask >> r) & 1) sacc[r] = -3.0e38f;
            }
#pragma unroll
            for (int r2 = 0; r2 < 8; r2++) {
                float p0 = exp2f(sacc[2 * r2]), p1 = exp2f(sacc[2 * r2 + 1]);
                ls0 += p0; ls1 += p1;
                u[sub * 8 + r2] = pack2r(p0, p1);
            }
        }

        // O^T += Vt P^T.  B(P)[n=q][k=16s+8h+j]; lane pair (l, l^32) holds all kv.
#pragma unroll
        for (int s = 0; s < 8; s++) {
            const int i0 = 8 * (s >> 1) + 4 * (s & 1);
            unsigned sA = h ? u[i0] : u[i0 + 2], sB = h ? u[i0 + 1] : u[i0 + 3];
            unsigned rA = __shfl_xor(sA, 32), rB = __shfl_xor(sB, 32);
            uint4v pu = { h ? rA : u[i0],     h ? rB : u[i0 + 1],
                          h ? u[i0 + 2] : rA, h ? u[i0 + 3] : rB };
            short8 pf = __builtin_bit_cast(short8, pu);
#pragma unroll
            for (int dt = 0; dt < 2; dt++) {       // A(Vt)[m=d][k=kv]: row dt*32+l31
                const int gv = dt * 8 + (l31 >> 2);
                const int cv = ((2 * s + h) ^ (l31 & 15)) * 8;
                short8 vf = *(const short8*)&Vs[buf][gv * 528 + (l31 & 3) * 128 + cv];
                accO[dt] = mfma32(vf, pf, accO[dt]);
            }
        }
    }

    // lane pair covers all 128 kv per iter -> one final half-wave reduce
    float lsum = ls0 + ls1;
    lsum += __shfl_xor(lsum, 32);
    const float inv = 1.f / lsum;

    // epilogue: O[token][head*64 + d], d = dt*32 + 8g + 4h + {0..3} -> 8B stores
    const int b = bh >> 3, head = bh & 7;
    const int token = b * 1024 + qrow;
#pragma unroll
    for (int dt = 0; dt < 2; dt++)
#pragma unroll
        for (int g = 0; g < 4; g++) {
            uint2v s2 = { pack2r(accO[dt][4 * g] * inv, accO[dt][4 * g + 1] * inv),
                          pack2r(accO[dt][4 * g + 2] * inv, accO[dt][4 * g + 3] * inv) };
            *(uint2v*)&O[token * 512 + head * 64 + dt * 32 + 8 * g + 4 * h] = s2;
        }
}

// ------------- launch --------------------------------------------------------------
extern "C" void kernel_launch(void* const* d_in, const int* in_sizes, int n_in,
                              void* d_out, int out_size, void* d_ws, size_t ws_size,
                              hipStream_t stream) {
    const float* x    = (const float*)d_in[0];   // 8192 x 512 fp32
    const float* wqkv = (const float*)d_in[1];   // 512 x 1536 fp32
    const float* temp = (const float*)d_in[2];   // scalar fp32
    const float* wout = (const float*)d_in[3];   // 512 x 512 fp32
    const float* bout = (const float*)d_in[4];   // 512 fp32
    float* out = (float*)d_out;                  // 8192 x 512 fp32

    short* ws  = (short*)d_ws;
    short* wt1 = ws;                  // 1536*512
    short* wt2 = wt1 + 786432;        // 512*512
    short* Qb  = wt2 + 262144;        // 64*1024*64
    short* Kb  = Qb  + 4194304;
    short* Vtb = Kb  + 4194304;       // V transposed: [bh][64][1024]
    short* Xb  = Vtb + 4194304;       // x as bf16; dead after GEMM1 ->
    short* Ob  = Xb;                  //   aliased by attention output (8192x512)

    prep<<<2304, 256, 0, stream>>>(x, wqkv, wout, Xb, wt1, wt2);

    dim3 g1(64, 12);
    gemm128<0><<<g1, 256, 0, stream>>>(Xb, wt1, temp, Qb, Kb, Vtb, nullptr, nullptr);

    attn_kernel<<<256, 512, 0, stream>>>(Qb, Kb, Vtb, Ob);

    dim3 g2(64, 4);
    gemm128<1><<<g2, 256, 0, stream>>>(Ob, wt2, nullptr, nullptr, nullptr, nullptr, out, bout);
}

// Round 12
// 139.772 us; speedup vs baseline: 1.0402x; 1.0402x over previous
//
#include <hip/hip_runtime.h>

// LSA: x(8,1024,512) -> qkv -> 8-head attention (N=1024, D=64, diag masked,
// learnable temperature) -> out proj. I/O fp32; bf16 MFMA, fp32 accum.
// B=8, N=1024, DIM=512, H=8, Dh=64, INNER=512.

typedef __attribute__((ext_vector_type(8)))  short    short8;
typedef __attribute__((ext_vector_type(8)))  __bf16   bf16x8;
typedef __attribute__((ext_vector_type(4)))  float    floatx4;
typedef __attribute__((ext_vector_type(16))) float    floatx16;
typedef __attribute__((ext_vector_type(4)))  unsigned uint4v;
typedef __attribute__((ext_vector_type(2)))  unsigned uint2v;

#define DEV static __device__ __forceinline__
#define AS1 __attribute__((address_space(1)))
#define AS3 __attribute__((address_space(3)))

DEV unsigned fbits(float f) { union { float f; unsigned u; } v; v.f = f; return v.u; }
DEV short f2bf_r(float f) {            // round-half-up f32->bf16: 2 ops
    return (short)((fbits(f) + 0x8000u) >> 16);
}
DEV unsigned pack2r(float a, float b) {  // [b|a] bf16 pair: add,add,v_perm = 3 ops
    return __builtin_amdgcn_perm(fbits(b) + 0x8000u, fbits(a) + 0x8000u, 0x07060302u);
}
DEV floatx4 mfma16(short8 a, short8 b, floatx4 c) {
    return __builtin_amdgcn_mfma_f32_16x16x32_bf16(
        __builtin_bit_cast(bf16x8, a), __builtin_bit_cast(bf16x8, b), c, 0, 0, 0);
}
DEV floatx16 mfma32(short8 a, short8 b, floatx16 c) {
    return __builtin_amdgcn_mfma_f32_32x32x16_bf16(
        __builtin_bit_cast(bf16x8, a), __builtin_bit_cast(bf16x8, b), c, 0, 0, 0);
}
// async global->LDS, 16B per lane. l must be the wave-uniform base (lane 0 slot).
DEV void async16(const void* g, void* l) {
    __builtin_amdgcn_global_load_lds((AS1 void*)(unsigned long long)g,
                                     (AS3 void*)l, 16, 0, 0);
}

// ------------- prep: x fp32->bf16 ; LDS-tiled transpose+convert of weights --------
__global__ void prep(const float* __restrict__ x, const float* __restrict__ wqkv,
                     const float* __restrict__ wout, short* __restrict__ Xb,
                     short* __restrict__ wt1, short* __restrict__ wt2) {
    const int bid = blockIdx.x, tid = threadIdx.x;
    if (bid < 2048) {                       // x: 4,194,304 elems, 8/thread
        int base = bid * 2048 + tid * 8;
        float4 f0 = *(const float4*)&x[base];
        float4 f1 = *(const float4*)&x[base + 4];
        uint4v s = { pack2r(f0.x, f0.y), pack2r(f0.z, f0.w),
                     pack2r(f1.x, f1.y), pack2r(f1.z, f1.w) };
        *(uint4v*)&Xb[base] = s;
        return;
    }
    // transpose 64x64 tiles: wqkv [512k][1536n] -> wt1 [1536][512];
    //                        wout [512k][512n]  -> wt2 [512][512]
    __shared__ short Ts[64][65];
    int t = bid - 2048;
    const float* src; short* dst; int srcld, n0, k0;
    if (t < 192) { int tn = t % 24, tk = t / 24; n0 = tn * 64; k0 = tk * 64;
                   src = wqkv; srcld = 1536; dst = wt1; }
    else { t -= 192; int tn = t & 7, tk = t >> 3; n0 = tn * 64; k0 = tk * 64;
           src = wout; srcld = 512; dst = wt2; }
#pragma unroll
    for (int it = 0; it < 16; it++) {       // coalesced read (consecutive n)
        int idx = it * 256 + tid, rk = idx >> 6, cn = idx & 63;
        Ts[cn][rk] = f2bf_r(src[(k0 + rk) * srcld + n0 + cn]);
    }
    __syncthreads();
#pragma unroll
    for (int it = 0; it < 16; it++) {       // coalesced write (consecutive k)
        int idx = it * 256 + tid, rn = idx >> 6, ck = idx & 63;
        dst[(n0 + rn) * 512 + k0 + ck] = Ts[rn][ck];
    }
}

// ------------- GEMM: C(8192 x N) = A(8192x512) * Bt(Nx512)^T ----------------------
// m97 pattern: unpadded LDS, global_load_lds width-16, XOR-chunk swizzle for
// conflict-free ds_read_b128. MODE 0: N=1536, LDS-routed epilogue -> Q,K,Vt (bf16,
// all 16B coalesced stores). MODE 1: N=512, fp32 bias + fp32 store.
// bounds(256,3): cap VGPR ~170 so all 768 gemm1 blocks are co-resident (3/CU).
template<int MODE>
__global__ __launch_bounds__(256, 3)
void gemm128(const short* __restrict__ A, const short* __restrict__ Bt,
             const float* __restrict__ temp,
             short* __restrict__ Qb, short* __restrict__ Kb, short* __restrict__ Vtb,
             float* __restrict__ Op, const float* __restrict__ bias) {
    union SMem {
        struct { short As[128 * 64]; short Bs[128 * 64]; } t;
        short Ts[128 * 130];                // epilogue re-layout scratch (+2 pad)
    };
    __shared__ __align__(16) SMem sm;

    const int tid  = threadIdx.x;
    const int lane = tid & 63, w = tid >> 6;
    const int wr = (w >> 1) * 64, wc = (w & 1) * 64;
    const int l15 = lane & 15, quad = lane >> 4;
    const int m0 = blockIdx.x * 128, n0 = blockIdx.y * 128;

    floatx4 acc[4][4];
#pragma unroll
    for (int i = 0; i < 4; i++)
#pragma unroll
        for (int j = 0; j < 4; j++) acc[i][j] = (floatx4)0.f;

    // staging: slot s holds row r=s>>3, chunk cc=s&7; LDS chunk cc = global chunk cc^(r&7)
    const int sr = (tid >> 3), scc = tid & 7;
    for (int kt = 0; kt < 512; kt += 64) {
#pragma unroll
        for (int it = 0; it < 4; it++) {
            int r = it * 32 + sr;                       // slot = it*256 + tid
            int gcol = kt + ((scc ^ (r & 7)) * 8);
            async16(&A[(m0 + r) * 512 + gcol], sm.t.As + (it * 256 + w * 64) * 8);
            async16(&Bt[(n0 + r) * 512 + gcol], sm.t.Bs + (it * 256 + w * 64) * 8);
        }
        __syncthreads();
#pragma unroll
        for (int k2 = 0; k2 < 2; k2++) {
            const int cS = ((k2 * 4 + quad) ^ (l15 & 7)) * 8;
            short8 af[4], bf[4];
#pragma unroll
            for (int i = 0; i < 4; i++) {
                af[i] = *(const short8*)&sm.t.As[(wr + i * 16 + l15) * 64 + cS];
                bf[i] = *(const short8*)&sm.t.Bs[(wc + i * 16 + l15) * 64 + cS];
            }
#pragma unroll
            for (int i = 0; i < 4; i++)
#pragma unroll
                for (int j = 0; j < 4; j++)
                    acc[i][j] = mfma16(af[i], bf[j], acc[i][j]);
        }
        __syncthreads();
    }

    // C/D layout: col = lane&15, row = quad*4 + reg
    if (MODE == 1) {
#pragma unroll
        for (int i = 0; i < 4; i++) {
            int mrow = m0 + wr + i * 16 + quad * 4;
#pragma unroll
            for (int j = 0; j < 4; j++) {
                int col = n0 + wc + j * 16 + l15;
                float b = bias[col];
#pragma unroll
                for (int r = 0; r < 4; r++)
                    Op[(mrow + r) * 512 + col] = acc[i][j][r] + b;
            }
        }
        return;
    }

    // MODE 0: route through LDS so every global store is a coalesced short8.
    const int which = n0 >> 9;                 // 0=Q 1=K 2=V
    const float qs = (which == 0) ? __expf(temp[0]) * 1.44269504089f : 1.f;
    const bool isV = (which == 2);
#pragma unroll
    for (int i = 0; i < 4; i++)
#pragma unroll
        for (int j = 0; j < 4; j++) {
            int c  = wc + j * 16 + l15;
            int tt = wr + i * 16 + quad * 4;
#pragma unroll
            for (int r = 0; r < 4; r++) {
                short v = f2bf_r(acc[i][j][r] * qs);
                if (isV) sm.Ts[c * 130 + tt + r] = v;        // [col][token]
                else     sm.Ts[(tt + r) * 130 + c] = v;      // [token][col]
            }
        }
    __syncthreads();
    const int bb = m0 >> 10, tloc = m0 & 1023;
#pragma unroll
    for (int it = 0; it < 8; it++) {
        int s = it * 256 + tid;                // 2048 strips of 8 shorts
        int a = s >> 4, b8 = s & 15;
        short8 v = *(const short8*)&sm.Ts[a * 130 + b8 * 8];
        if (isV) {                             // a = col (vcol), b8*8 = token offset
            int vcol = n0 - 1024 + a;
            int bh = bb * 8 + (vcol >> 6), d = vcol & 63;
            *(short8*)&Vtb[(bh * 64 + d) * 1024 + tloc + b8 * 8] = v;
        } else {                               // a = token row, b8*8 = col offset
            int col = n0 + b8 * 8;
            int bh = bb * 8 + ((col >> 6) & 7), d0 = col & 63;
            short* dst = (which == 0) ? Qb : Kb;
            *(short8*)&dst[(bh * 1024 + tloc + a) * 64 + d0] = v;
        }
    }
}

// ------------- flash attention v8 (r10 winner, reverted from r11) ------------------
// grid 512 = bh(64) x qtile(8), bh = blk & 63 (XCD-local: stride-64 = same XCD).
// 2 blocks/CU x 4 waves: the co-resident block hides the other's barrier drain --
// r11's 1-block/CU merge removed that overlap and regressed (+5.5 us).
// Pipeline: barrier (drains tile-j loads) -> prefetch tile j+1 into other buffer
// -> compute tile j. One barrier per kv-iter.
__global__ __launch_bounds__(256, 2)
void attn_kernel(const short* __restrict__ Q, const short* __restrict__ Kb,
                 const short* __restrict__ Vt, short* __restrict__ O) {
    __shared__ __align__(16) short Ks[2][16 * 528];   // K tiles [kv128][d64]  2x16.9 KB
    __shared__ __align__(16) short Vs[2][16 * 528];   // Vt tiles [d64][kv128] 2x16.9 KB

    const int tid  = threadIdx.x;
    const int lane = tid & 63, w = tid >> 6;       // 4 waves
    const int l31 = lane & 31, h = lane >> 5;
    const int bh = blockIdx.x & 63, qt = blockIdx.x >> 6;   // XCD-local swizzle
    const int qrow = qt * 128 + w * 32 + l31;      // this lane's q row

    // staging lane constants
    const int krow_off = lane >> 3, kchunk = ((lane & 7) ^ (lane >> 3)) * 8;
    const int vrow_off = lane >> 4, vcs = lane & 15;
    const short* Kbase = Kb + bh * 65536;
    const short* Vbase = Vt + bh * 65536;

    // prefetch tile 0 into buffer 0
#pragma unroll
    for (int it = 0; it < 4; it++) {
        int g = it * 4 + w;
        async16(&Kbase[(g * 8 + krow_off) * 64 + kchunk], Ks[0] + g * 528);
        int vr = g * 4 + vrow_off;
        async16(&Vbase[vr * 1024 + ((vcs ^ (vr & 15)) * 8)], Vs[0] + g * 528);
    }

    // Q B-frag (pre-scaled by exp(T)*log2e): B[n=q=lane&31][k=ks*16+h*8+j]
    const short* Qp = Q + (bh * 1024 + qrow) * 64;
    short8 qf[4];
#pragma unroll
    for (int ks = 0; ks < 4; ks++)
        qf[ks] = *(const short8*)&Qp[ks * 16 + h * 8];

    floatx16 accO[2];                              // O^T: d=dt*32+(reg&3)+8(reg>>2)+4h
    accO[0] = (floatx16)0.f; accO[1] = (floatx16)0.f;
    float ls0 = 0.f, ls1 = 0.f;                    // split row-sum chains (ILP)

    // diagonal: masked element of S^T sits at sub==w, lane h==qbit2, reg from q bits
    const unsigned lanemask =
        (h == ((l31 >> 2) & 1)) ? (1u << ((l31 & 3) | (((l31 >> 3) & 3) << 2))) : 0u;

    for (int j = 0; j < 8; j++) {
        const int buf = j & 1;
        __syncthreads();                           // tile j landed; all past tile j-1

        if (j < 7) {                               // prefetch tile j+1 into other buf
            const int kv1 = (j + 1) * 128;
#pragma unroll
            for (int it = 0; it < 4; it++) {
                int g = it * 4 + w;
                async16(&Kbase[(kv1 + g * 8 + krow_off) * 64 + kchunk],
                        Ks[buf ^ 1] + g * 528);
                int vr = g * 4 + vrow_off;
                async16(&Vbase[vr * 1024 + kv1 + ((vcs ^ (vr & 15)) * 8)],
                        Vs[buf ^ 1] + g * 528);
            }
        }

        // S^T per 32-kv subtile; exp2 + pack immediately (keeps regs low)
        unsigned u[32];                            // P pairs: u[sub*8 + g*2 + t]
#pragma unroll
        for (int sub = 0; sub < 4; sub++) {
            floatx16 sacc = (floatx16)0.f;
#pragma unroll
            for (int ks = 0; ks < 4; ks++) {       // A(K)[m=kv][k]: row sub*32+l31
                const int grp = sub * 4 + (l31 >> 3);
                const int ck = ((2 * ks + h) ^ (l31 & 7)) * 8;
                short8 kf = *(const short8*)&Ks[buf][grp * 528 + (l31 & 7) * 64 + ck];
                sacc = mfma32(kf, qf[ks], sacc);
            }
            if (j == qt && sub == w) {             // diagonal mask
#pragma unroll
                for (int r = 0; r < 16; r++)
                    if ((lanemask >> r) & 1) sacc[r] = -3.0e38f;
            }
#pragma unroll
            for (int r2 = 0; r2 < 8; r2++) {
                float p0 = exp2f(sacc[2 * r2]), p1 = exp2f(sacc[2 * r2 + 1]);
                ls0 += p0; ls1 += p1;
                u[sub * 8 + r2] = pack2r(p0, p1);
            }
        }

        // O^T += Vt P^T.  B(P)[n=q][k=16s+8h+j]; lane pair (l, l^32) holds all kv.
#pragma unroll
        for (int s = 0; s < 8; s++) {
            const int i0 = 8 * (s >> 1) + 4 * (s & 1);
            unsigned sA = h ? u[i0] : u[i0 + 2], sB = h ? u[i0 + 1] : u[i0 + 3];
            unsigned rA = __shfl_xor(sA, 32), rB = __shfl_xor(sB, 32);
            uint4v pu = { h ? rA : u[i0],     h ? rB : u[i0 + 1],
                          h ? u[i0 + 2] : rA, h ? u[i0 + 3] : rB };
            short8 pf = __builtin_bit_cast(short8, pu);
#pragma unroll
            for (int dt = 0; dt < 2; dt++) {       // A(Vt)[m=d][k=kv]: row dt*32+l31
                const int gv = dt * 8 + (l31 >> 2);
                const int cv = ((2 * s + h) ^ (l31 & 15)) * 8;
                short8 vf = *(const short8*)&Vs[buf][gv * 528 + (l31 & 3) * 128 + cv];
                accO[dt] = mfma32(vf, pf, accO[dt]);
            }
        }
    }

    // lane pair covers all 128 kv per iter -> one final half-wave reduce
    float lsum = ls0 + ls1;
    lsum += __shfl_xor(lsum, 32);
    const float inv = 1.f / lsum;

    // epilogue: O[token][head*64 + d], d = dt*32 + 8g + 4h + {0..3} -> 8B stores
    const int b = bh >> 3, head = bh & 7;
    const int token = b * 1024 + qrow;
#pragma unroll
    for (int dt = 0; dt < 2; dt++)
#pragma unroll
        for (int g = 0; g < 4; g++) {
            uint2v s2 = { pack2r(accO[dt][4 * g] * inv, accO[dt][4 * g + 1] * inv),
                          pack2r(accO[dt][4 * g + 2] * inv, accO[dt][4 * g + 3] * inv) };
            *(uint2v*)&O[token * 512 + head * 64 + dt * 32 + 8 * g + 4 * h] = s2;
        }
}

// ------------- launch --------------------------------------------------------------
extern "C" void kernel_launch(void* const* d_in, const int* in_sizes, int n_in,
                              void* d_out, int out_size, void* d_ws, size_t ws_size,
                              hipStream_t stream) {
    const float* x    = (const float*)d_in[0];   // 8192 x 512 fp32
    const float* wqkv = (const float*)d_in[1];   // 512 x 1536 fp32
    const float* temp = (const float*)d_in[2];   // scalar fp32
    const float* wout = (const float*)d_in[3];   // 512 x 512 fp32
    const float* bout = (const float*)d_in[4];   // 512 fp32
    float* out = (float*)d_out;                  // 8192 x 512 fp32

    short* ws  = (short*)d_ws;
    short* wt1 = ws;                  // 1536*512
    short* wt2 = wt1 + 786432;        // 512*512
    short* Qb  = wt2 + 262144;        // 64*1024*64
    short* Kb  = Qb  + 4194304;
    short* Vtb = Kb  + 4194304;       // V transposed: [bh][64][1024]
    short* Xb  = Vtb + 4194304;       // x as bf16; dead after GEMM1 ->
    short* Ob  = Xb;                  //   aliased by attention output (8192x512)

    prep<<<2304, 256, 0, stream>>>(x, wqkv, wout, Xb, wt1, wt2);

    dim3 g1(64, 12);
    gemm128<0><<<g1, 256, 0, stream>>>(Xb, wt1, temp, Qb, Kb, Vtb, nullptr, nullptr);

    attn_kernel<<<512, 256, 0, stream>>>(Qb, Kb, Vtb, Ob);

    dim3 g2(64, 4);
    gemm128<1><<<g2, 256, 0, stream>>>(Ob, wt2, nullptr, nullptr, nullptr, nullptr, out, bout);
}